// Round 8
// baseline (98.703 us; speedup 1.0000x reference)
//
#include <hip/hip_runtime.h>
#include <math.h>

#define N_SPK 1024
#define M_UTT 32
#define M_ENR 16
#define M_TEST 16
#define D 512
#define N_TEST_ROWS (N_SPK * M_TEST)   // 16384
#define NBLK_GEMM 512

// gemm: TRANSPOSED C' = test_n (16384xK) . cent_n^T (Kx1024), MX-fp8 e4m3
// (scale = 1.0) via mfma_scale_f32_32x32x64_f8f6f4. Block 256M x 128N,
// 8 waves (4M x 2N), wave tile 64x64 -> acc 4 x f32x16. cent panel (64 KB)
// LDS-resident XOR-swizzled; test streamed L2->reg (32 B/lane/frag).
// Row-sum reduction runs along the REGISTER axis (pure VALU), so the
// epilogue needs only 1 shuffle per column-tile. Finalize fused via
// last-block counter.

typedef __attribute__((ext_vector_type(4))) float f32x4;
typedef __attribute__((ext_vector_type(4))) int i32x4;
typedef __attribute__((ext_vector_type(8))) int i32x8;
typedef __attribute__((ext_vector_type(16))) float f32x16;

typedef const __attribute__((address_space(1))) void g_void;
typedef __attribute__((address_space(3))) void lds_void;

// ---- OCP e4m3fn encode, RNE ------------------------------------------------
__device__ __forceinline__ unsigned int f2e4m3(float f) {
    unsigned int u = __float_as_uint(f);
    const unsigned int s = (u >> 31) << 7;
    float a = fabsf(f);
    if (a >= 448.f) return s | 0x7E;                 // saturate to max normal
    unsigned int ua = u & 0x7FFFFFFFu;
    int e = (int)(ua >> 23) - 127;
    if (e >= -6) {                                   // normal range
        ua += 0x7FFFF + ((ua >> 20) & 1);            // RNE at mantissa bit 20
        e = (int)(ua >> 23) - 127;
        if (e > 8) return s | 0x7E;
        const unsigned int m = (ua >> 20) & 7;
        return s | ((unsigned int)(e + 7) << 3) | m;
    } else {                                         // subnormal: k * 2^-9
        const int k = (int)rintf(a * 512.f);
        if (k >= 8) return s | 0x08;                 // min normal
        return s | (unsigned int)k;
    }
}

// ---------------------------------------------------------------------------
// Kernel 1: centroids + test-row normalize -> fp8; zero accumulators+counter.
// ---------------------------------------------------------------------------
__global__ __launch_bounds__(256) void prep_kernel(const float* __restrict__ emb,
                                                   unsigned char* __restrict__ cent8,
                                                   unsigned char* __restrict__ test8,
                                                   float* __restrict__ g_row,
                                                   float* __restrict__ g_pos,
                                                   unsigned int* __restrict__ cnt) {
    const int b = blockIdx.x;
    const int tid = threadIdx.x;
    const int lane = tid & 63;
    const int wid = tid >> 6;

    if (b < 4) {   // zero global accumulators (replaces a fill dispatch)
        g_row[b * 256 + tid] = 0.f;
        g_pos[b * 256 + tid] = 0.f;
        if (b == 0 && tid == 0) *cnt = 0u;
    }

    if (b < N_SPK) {
        const float* base = emb + (size_t)b * M_UTT * D;
        float a0 = 0.f, a1 = 0.f;
#pragma unroll
        for (int u = 0; u < M_ENR; ++u) {
            a0 += base[u * D + tid];
            a1 += base[u * D + tid + 256];
        }
        a0 *= (1.f / 16.f);
        a1 *= (1.f / 16.f);
        float ss = a0 * a0 + a1 * a1;
#pragma unroll
        for (int m = 1; m < 64; m <<= 1) ss += __shfl_xor(ss, m, 64);
        __shared__ float wss[4];
        if (lane == 0) wss[wid] = ss;
        __syncthreads();
        const float tot = wss[0] + wss[1] + wss[2] + wss[3];
        const float inv = 1.f / fmaxf(sqrtf(tot), 1e-8f);
        cent8[b * D + tid] = (unsigned char)f2e4m3(a0 * inv);
        cent8[b * D + tid + 256] = (unsigned char)f2e4m3(a1 * inv);
    } else {
        const int r = (b - N_SPK) * 4 + wid;   // test row 0..16383
        const int s = r >> 4, t = r & 15;
        const float* row = emb + ((size_t)s * M_UTT + M_ENR + t) * D;
        const f32x4* rv = (const f32x4*)row;
        const f32x4 v0 = rv[lane * 2];
        const f32x4 v1 = rv[lane * 2 + 1];
        float ss = v0[0]*v0[0] + v0[1]*v0[1] + v0[2]*v0[2] + v0[3]*v0[3]
                 + v1[0]*v1[0] + v1[1]*v1[1] + v1[2]*v1[2] + v1[3]*v1[3];
#pragma unroll
        for (int m = 1; m < 64; m <<= 1) ss += __shfl_xor(ss, m, 64);
        const float inv = 1.f / fmaxf(sqrtf(ss), 1e-8f);
        unsigned long long ob = 0ull;
        ob |= (unsigned long long)f2e4m3(v0[0] * inv);
        ob |= (unsigned long long)f2e4m3(v0[1] * inv) << 8;
        ob |= (unsigned long long)f2e4m3(v0[2] * inv) << 16;
        ob |= (unsigned long long)f2e4m3(v0[3] * inv) << 24;
        ob |= (unsigned long long)f2e4m3(v1[0] * inv) << 32;
        ob |= (unsigned long long)f2e4m3(v1[1] * inv) << 40;
        ob |= (unsigned long long)f2e4m3(v1[2] * inv) << 48;
        ob |= (unsigned long long)f2e4m3(v1[3] * inv) << 56;
        *(unsigned long long*)&test8[(size_t)r * D + lane * 8] = ob;
    }
}

// ---------------------------------------------------------------------------
// Kernel 2: transposed MX-fp8 GEMM + fused exp/speaker-sum + fused finalize.
// ---------------------------------------------------------------------------
__global__ __launch_bounds__(512) void gemm_kernel(const unsigned char* __restrict__ A,   // test8 16384x512
                                                   const unsigned char* __restrict__ Bc,  // cent8 1024x512
                                                   const float* __restrict__ alpha_p,
                                                   const float* __restrict__ beta_p,
                                                   float* __restrict__ g_row,
                                                   float* __restrict__ g_pos,
                                                   unsigned int* __restrict__ cnt,
                                                   float* __restrict__ out) {
    __shared__ __align__(16) unsigned char Bs[128 * 512];   // cent panel, swizzled
    __shared__ float tsum[128];
    __shared__ float psum[128];
    __shared__ unsigned int last_flag;
    __shared__ float ws2[8];

    const int tid = threadIdx.x;
    const int lane = tid & 63;
    const int w = tid >> 6;          // 8 waves: 4M x 2N
    const int wr = w >> 1;           // 0..3  (M offset wr*64)
    const int wc = w & 1;            // 0..1  (N offset wc*64)
    const int hh = lane >> 5;        // k-half
    const int l31 = lane & 31;

    // XCD-chunked decode: xcd = bid&7 gets contiguous bm range (1 MB test in L2).
    const int bid = blockIdx.x;
    const int idx = bid >> 3;
    const int bm = (bid & 7) * 8 + (idx & 7);   // 0..63  (256 test rows each)
    const int bn = idx >> 3;                    // 0..7   (128 speakers each)
    const bool has_diag = (bn == (bm >> 3));

    // ---- stage cent panel: LDS[r][g16] = cent[bn*128+r][g16 ^ (r&31)]
#pragma unroll
    for (int it = 0; it < 8; ++it) {
        const int q = it * 8 + w;                       // 0..63, rows 2q,2q+1
        const int r_l = 2 * q + hh;
        const int src_col = (l31 ^ (r_l & 31)) << 4;
        __builtin_amdgcn_global_load_lds(
            (g_void*)&Bc[(size_t)(bn * 128 + r_l) * D + src_col],
            (lds_void*)&Bs[(2 * q) * 512],              // + lane*16B implicit
            16, 0, 0);
    }
    if (tid < 128) { tsum[tid] = 0.f; psum[tid] = 0.f; }

    const float alpha = *alpha_p;
    const float beta = *beta_p;

    const int mrow0 = bm * 256 + wr * 64;   // global test-row base of this wave
    const int ncol0 = bn * 128 + wc * 64;   // global speaker base of this wave

    // per-lane test pointers (rows mrow0 + mi*32 + l31, k-bytes hh*32 + ...)
    const unsigned char* pa0 = A + (size_t)(mrow0 + l31) * D + hh * 32;
    const unsigned char* pa1 = A + (size_t)(mrow0 + 32 + l31) * D + hh * 32;
    const int rb0 = (wc * 64 + l31) * 512;          // LDS byte base, cent row
    const int rb1 = rb0 + 32 * 512;

    f32x16 acc00 = (f32x16)(0.0f), acc01 = (f32x16)(0.0f);
    f32x16 acc10 = (f32x16)(0.0f), acc11 = (f32x16)(0.0f);
    i32x8 A00, A01, A10, A11, B00, B01, B10, B11;

#define ALOAD(d0, d1, s)                                                        \
    { i32x4 lo = *(const i32x4*)(pa0 + (s) * 64);                               \
      i32x4 hi = *(const i32x4*)(pa0 + (s) * 64 + 16);                          \
      d0 = __builtin_shufflevector(lo, hi, 0, 1, 2, 3, 4, 5, 6, 7);             \
      lo = *(const i32x4*)(pa1 + (s) * 64);                                     \
      hi = *(const i32x4*)(pa1 + (s) * 64 + 16);                                \
      d1 = __builtin_shufflevector(lo, hi, 0, 1, 2, 3, 4, 5, 6, 7); }

#define BLOAD(d0, d1, s)                                                        \
    { const int G0 = (s) * 4 + hh * 2;                                          \
      i32x4 lo = *(const i32x4*)&Bs[rb0 + ((G0 ^ l31) << 4)];                   \
      i32x4 hi = *(const i32x4*)&Bs[rb0 + (((G0 + 1) ^ l31) << 4)];             \
      d0 = __builtin_shufflevector(lo, hi, 0, 1, 2, 3, 4, 5, 6, 7);             \
      lo = *(const i32x4*)&Bs[rb1 + ((G0 ^ l31) << 4)];                         \
      hi = *(const i32x4*)&Bs[rb1 + (((G0 + 1) ^ l31) << 4)];                   \
      d1 = __builtin_shufflevector(lo, hi, 0, 1, 2, 3, 4, 5, 6, 7); }

#define MSTEP(Aa0, Aa1, Bb0, Bb1)                                               \
    acc00 = __builtin_amdgcn_mfma_scale_f32_32x32x64_f8f6f4(                    \
        Aa0, Bb0, acc00, 0, 0, 0, 0x7F7F7F7F, 0, 0x7F7F7F7F);                   \
    acc01 = __builtin_amdgcn_mfma_scale_f32_32x32x64_f8f6f4(                    \
        Aa0, Bb1, acc01, 0, 0, 0, 0x7F7F7F7F, 0, 0x7F7F7F7F);                   \
    acc10 = __builtin_amdgcn_mfma_scale_f32_32x32x64_f8f6f4(                    \
        Aa1, Bb0, acc10, 0, 0, 0, 0x7F7F7F7F, 0, 0x7F7F7F7F);                   \
    acc11 = __builtin_amdgcn_mfma_scale_f32_32x32x64_f8f6f4(                    \
        Aa1, Bb1, acc11, 0, 0, 0, 0x7F7F7F7F, 0, 0x7F7F7F7F);

    ALOAD(A00, A01, 0);
    __syncthreads();                      // cent panel staged
    BLOAD(B00, B01, 0); ALOAD(A10, A11, 1); BLOAD(B10, B11, 1);

    MSTEP(A00, A01, B00, B01); ALOAD(A00, A01, 2); BLOAD(B00, B01, 2);
    MSTEP(A10, A11, B10, B11); ALOAD(A10, A11, 3); BLOAD(B10, B11, 3);
    MSTEP(A00, A01, B00, B01); ALOAD(A00, A01, 4); BLOAD(B00, B01, 4);
    MSTEP(A10, A11, B10, B11); ALOAD(A10, A11, 5); BLOAD(B10, B11, 5);
    MSTEP(A00, A01, B00, B01); ALOAD(A00, A01, 6); BLOAD(B00, B01, 6);
    MSTEP(A10, A11, B10, B11); ALOAD(A10, A11, 7); BLOAD(B10, B11, 7);
    MSTEP(A00, A01, B00, B01);
    MSTEP(A10, A11, B10, B11);
#undef ALOAD
#undef BLOAD
#undef MSTEP

    // ---- epilogue: e = exp(alpha*s+beta); per-SPEAKER sums.
    // C/D 32x32 layout: col = lane&31, row = (reg&3) + 8*(reg>>2) + 4*(lane>>5)
    // Speaker = column -> sum over rows = sum over REGS (VALU) + 1 shuffle.
#define EPI(ACC, mi, ni)                                                        \
    {                                                                           \
        float t = 0.f, p = 0.f;                                                 \
        _Pragma("unroll") for (int r = 0; r < 16; ++r) {                        \
            const float e = __expf(fmaf(alpha, ACC[r], beta));                  \
            t += e;                                                             \
            if (has_diag) {                                                     \
                const int row = mrow0 + (mi) * 32 + (r & 3) + 8 * (r >> 2) + 4 * hh; \
                p += (((row >> 4) == (ncol0 + (ni) * 32 + l31)) ? e : 0.f);     \
            }                                                                   \
        }                                                                       \
        t += __shfl_xor(t, 32, 64);                                             \
        if (lane < 32) atomicAdd(&tsum[wc * 64 + (ni) * 32 + l31], t);          \
        if (has_diag) {                                                         \
            p += __shfl_xor(p, 32, 64);                                         \
            if (lane < 32) atomicAdd(&psum[wc * 64 + (ni) * 32 + l31], p);      \
        }                                                                       \
    }
    EPI(acc00, 0, 0) EPI(acc01, 0, 1) EPI(acc10, 1, 0) EPI(acc11, 1, 1)
#undef EPI

    __syncthreads();
    if (tid < 128) {
        atomicAdd(&g_row[bn * 128 + tid], tsum[tid]);
        if (has_diag) atomicAdd(&g_pos[bn * 128 + tid], psum[tid]);
    }

    // ---- fused finalize: last block computes the loss.
    __threadfence();
    if (tid == 0) last_flag = (atomicAdd(cnt, 1u) == (NBLK_GEMM - 1)) ? 1u : 0u;
    __syncthreads();
    if (last_flag) {
        __threadfence();
        float v = 0.f;
        for (int i = tid; i < N_SPK; i += 512) {
            const float pos = g_pos[i];
            const float neg = g_row[i] - pos;
            v += logf(fmaxf(neg, 1e-30f)) - logf(fmaxf(pos, 1e-30f));
        }
#pragma unroll
        for (int m = 1; m < 64; m <<= 1) v += __shfl_xor(v, m, 64);
        if (lane == 0) ws2[w] = v;
        __syncthreads();
        if (tid == 0) {
            float s = 0.f;
#pragma unroll
            for (int j = 0; j < 8; ++j) s += ws2[j];
            out[0] = s * (1.f / 1024.f);
        }
    }
}

extern "C" void kernel_launch(void* const* d_in, const int* in_sizes, int n_in,
                              void* d_out, int out_size, void* d_ws, size_t ws_size,
                              hipStream_t stream) {
    const float* emb = (const float*)d_in[0];
    // d_in[1] = labels (unused; structure fixed by construction)
    const float* alpha_p = (const float*)d_in[2];
    const float* beta_p = (const float*)d_in[3];

    unsigned char* cent8 = (unsigned char*)d_ws;                 // 512 KB
    unsigned char* test8 = cent8 + (size_t)N_SPK * D;            // 8 MB
    float* g_row = (float*)(test8 + (size_t)N_TEST_ROWS * D);
    float* g_pos = g_row + N_SPK;
    unsigned int* cnt = (unsigned int*)(g_pos + N_SPK);

    prep_kernel<<<N_SPK + N_TEST_ROWS / 4, 256, 0, stream>>>(emb, cent8, test8,
                                                             g_row, g_pos, cnt);

    gemm_kernel<<<NBLK_GEMM, 512, 0, stream>>>(test8, cent8, alpha_p, beta_p,
                                               g_row, g_pos, cnt, (float*)d_out);
}

// Round 9
// 71.355 us; speedup vs baseline: 1.3833x; 1.3833x over previous
//
#include <hip/hip_runtime.h>
#include <math.h>

#define N_SPK 1024
#define M_UTT 32
#define M_ENR 16
#define M_TEST 16
#define D 512
#define N_TEST_ROWS (N_SPK * M_TEST)   // 16384
#define NBLK_GEMM 256

// gemm: block = 512 thr (8 waves), tile 128spk x 512test, wave = 128 x 64.
// grid = 8 x 32 = 256 blocks = 1 per CU. A (cent) panel LDS-resident
// (XOR-swizzled), B (test) streamed L2->reg (2-ring), barrier-free K-loop.
// MFMA operands SWAPPED (mfma(bf, af)) so D = test x spk: speaker axis lands
// on lane&15 and per-speaker reduction is VALU-over-regs + 2 shuffles.
// Finalize fused into the last gemm block (atomic counter).

typedef __attribute__((ext_vector_type(4))) float f32x4;
typedef __attribute__((ext_vector_type(8))) short short8;
typedef __attribute__((ext_vector_type(8))) unsigned short ushort8;

typedef const __attribute__((address_space(1))) void g_void;
typedef __attribute__((address_space(3))) void lds_void;

__device__ __forceinline__ unsigned short f2bf(float f) {
    unsigned int u = __float_as_uint(f);
    u += 0x7FFF + ((u >> 16) & 1);   // round-to-nearest-even
    return (unsigned short)(u >> 16);
}

// ---------------------------------------------------------------------------
// Kernel 1: centroids + test-row normalize; blocks [0,4) zero g_row/g_pos/cnt.
// ---------------------------------------------------------------------------
__global__ __launch_bounds__(256) void prep_kernel(const float* __restrict__ emb,
                                                   unsigned short* __restrict__ cent,
                                                   unsigned short* __restrict__ test,
                                                   float* __restrict__ g_row,
                                                   float* __restrict__ g_pos,
                                                   unsigned int* __restrict__ cnt) {
    const int b = blockIdx.x;
    const int tid = threadIdx.x;
    const int lane = tid & 63;
    const int wid = tid >> 6;

    if (b < 4) {
        g_row[b * 256 + tid] = 0.f;
        g_pos[b * 256 + tid] = 0.f;
        if (b == 0 && tid == 0) *cnt = 0u;
    }

    if (b < N_SPK) {
        const float2* base2 = (const float2*)(emb + (size_t)b * M_UTT * D);
        float a0 = 0.f, a1 = 0.f;
#pragma unroll
        for (int u = 0; u < M_ENR; ++u) {
            const float2 v = base2[u * 256 + tid];   // cols 2tid, 2tid+1
            a0 += v.x; a1 += v.y;
        }
        a0 *= (1.f / 16.f);
        a1 *= (1.f / 16.f);
        float ss = a0 * a0 + a1 * a1;
#pragma unroll
        for (int m = 1; m < 64; m <<= 1) ss += __shfl_xor(ss, m, 64);
        __shared__ float wss[4];
        if (lane == 0) wss[wid] = ss;
        __syncthreads();
        const float tot = wss[0] + wss[1] + wss[2] + wss[3];
        const float inv = 1.f / fmaxf(sqrtf(tot), 1e-8f);
        ushort2 o2;
        o2.x = f2bf(a0 * inv);
        o2.y = f2bf(a1 * inv);
        *(ushort2*)&cent[b * D + 2 * tid] = o2;
    } else {
        const int r = (b - N_SPK) * 4 + wid;   // test row 0..16383
        const int s = r >> 4, t = r & 15;
        const float* row = emb + ((size_t)s * M_UTT + M_ENR + t) * D;
        const f32x4* rv = (const f32x4*)row;
        const f32x4 v0 = rv[lane * 2];
        const f32x4 v1 = rv[lane * 2 + 1];
        float ss = v0[0]*v0[0] + v0[1]*v0[1] + v0[2]*v0[2] + v0[3]*v0[3]
                 + v1[0]*v1[0] + v1[1]*v1[1] + v1[2]*v1[2] + v1[3]*v1[3];
#pragma unroll
        for (int m = 1; m < 64; m <<= 1) ss += __shfl_xor(ss, m, 64);
        const float inv = 1.f / fmaxf(sqrtf(ss), 1e-8f);
        ushort8 o;
        o[0] = f2bf(v0[0] * inv); o[1] = f2bf(v0[1] * inv);
        o[2] = f2bf(v0[2] * inv); o[3] = f2bf(v0[3] * inv);
        o[4] = f2bf(v1[0] * inv); o[5] = f2bf(v1[1] * inv);
        o[6] = f2bf(v1[2] * inv); o[7] = f2bf(v1[3] * inv);
        *(ushort8*)&test[(size_t)r * D + lane * 8] = o;
    }
}

// ---------------------------------------------------------------------------
// Kernel 2: R3-structure GEMM, swapped-operand epilogue, fused finalize.
// ---------------------------------------------------------------------------
__global__ __launch_bounds__(512, 1) void gemm_kernel(const unsigned short* __restrict__ A,  // cent 1024x512
                                                      const unsigned short* __restrict__ B,  // test 16384x512
                                                      const float* __restrict__ alpha_p,
                                                      const float* __restrict__ beta_p,
                                                      float* __restrict__ g_row,
                                                      float* __restrict__ g_pos,
                                                      unsigned int* __restrict__ cnt,
                                                      float* __restrict__ out) {
    __shared__ __align__(16) unsigned short As[128 * 512];   // 128 KB, swizzled
    __shared__ float tsum[128];
    __shared__ float psum[128];
    __shared__ unsigned int last_flag;
    __shared__ float ws2[8];

    const int tid = threadIdx.x;
    const int lane = tid & 63;
    const int w = tid >> 6;          // wave 0..7, owns test cols [w*64, +64)
    const int l15 = lane & 15;

    const int raw = blockIdx.x;
    const int wg = (raw & 7) * 32 + (raw >> 3);   // XCD swizzle (8 x 32)
    const int bi = wg & 7;           // speaker panel (128 rows)
    const int bj = wg >> 3;          // test panel (512 cols)
    const int row0 = bi * 128, col0 = bj * 512;
    const bool has_diag = ((bj >> 2) == bi);

    // ---- stage cent panel once: LDS[r][e] = A[row0+r][ e ^ ((r&7)<<3) ]
#pragma unroll
    for (int it = 0; it < 16; ++it) {
        const int r = it * 8 + w;
        const int src = (row0 + r) * D + ((lane * 8) ^ ((r & 7) << 3));
        __builtin_amdgcn_global_load_lds((g_void*)&A[src],
                                         (lds_void*)&As[r * D], 16, 0, 0);
    }
    if (tid < 128) { tsum[tid] = 0.f; psum[tid] = 0.f; }

    const float alpha = *alpha_p;
    const float beta = *beta_p;

    const int bcol = col0 + w * 64;
    const unsigned short* bp[4];
#pragma unroll
    for (int ni = 0; ni < 4; ++ni)
        bp[ni] = &B[(size_t)(bcol + ni * 16 + l15) * D + (lane >> 4) * 8];

    // swizzled LDS read offset: (kk + (lane>>4)*8) ^ ((lane&7)<<3) = kk ^ hs
    const int hs = ((lane >> 4) * 8) ^ ((lane & 7) << 3);
    const int arow_base = l15 * D;

    f32x4 acc[8][4] = {};
    short8 b0[4], b1[4];

#define LOADB(dst, kk)                                              \
    {                                                               \
        _Pragma("unroll") for (int ni = 0; ni < 4; ++ni)            \
            dst[ni] = *(const short8*)(bp[ni] + (kk));              \
    }

    // SWAPPED operands: D = bf (test, as M) x af (cent, as N).
    // D layout: col(=speaker) = lane&15, row(=test) = (lane>>4)*4 + reg.
#define STEP(bfr, kk)                                                          \
    {                                                                          \
        const int ofs_ = (kk) ^ hs;                                            \
        _Pragma("unroll") for (int mi = 0; mi < 8; ++mi) {                     \
            const short8 af_ = *(const short8*)&As[mi * 16 * D + arow_base + ofs_]; \
            _Pragma("unroll") for (int ni = 0; ni < 4; ++ni)                   \
                acc[mi][ni] = __builtin_amdgcn_mfma_f32_16x16x32_bf16(         \
                    bfr[ni], af_, acc[mi][ni], 0, 0, 0);                       \
        }                                                                      \
    }

    LOADB(b0, 0); LOADB(b1, 32);
    __syncthreads();   // A staged

    for (int ko = 0; ko < D; ko += 64) {
        STEP(b0, ko);       LOADB(b0, (ko + 64) & (D - 1));
        STEP(b1, ko + 32);  LOADB(b1, (ko + 96) & (D - 1));
    }
#undef LOADB
#undef STEP

    // ---- epilogue: e = exp(alpha*s + beta); per-SPEAKER sums.
    // speaker = row0 + mi*16 + l15 ; test col = bcol + ni*16 + (lane>>4)*4 + r
#pragma unroll
    for (int mi = 0; mi < 8; ++mi) {
        const int gs = row0 + mi * 16 + l15;
        float t = 0.f, p = 0.f;
#pragma unroll
        for (int ni = 0; ni < 4; ++ni) {
#pragma unroll
            for (int r = 0; r < 4; ++r) {
                const float e = __expf(fmaf(alpha, acc[mi][ni][r], beta));
                t += e;
                if (has_diag) {
                    const int tc = bcol + ni * 16 + ((lane >> 4) << 2) + r;
                    p += ((tc >> 4) == gs) ? e : 0.f;
                }
            }
        }
        t += __shfl_xor(t, 16, 64);
        t += __shfl_xor(t, 32, 64);
        if (lane < 16) atomicAdd(&tsum[mi * 16 + l15], t);
        if (has_diag) {
            p += __shfl_xor(p, 16, 64);
            p += __shfl_xor(p, 32, 64);
            if (lane < 16) atomicAdd(&psum[mi * 16 + l15], p);
        }
    }
    __syncthreads();
    if (tid < 128) {
        atomicAdd(&g_row[row0 + tid], tsum[tid]);
        if (has_diag) atomicAdd(&g_pos[row0 + tid], psum[tid]);
    }

    // ---- fused finalize: last block computes the loss.
    __threadfence();
    if (tid == 0) last_flag = (atomicAdd(cnt, 1u) == (NBLK_GEMM - 1)) ? 1u : 0u;
    __syncthreads();
    if (last_flag) {
        __threadfence();
        float v = 0.f;
        for (int i = tid; i < N_SPK; i += 512) {
            const float pos = g_pos[i];
            const float neg = g_row[i] - pos;
            v += logf(fmaxf(neg, 1e-30f)) - logf(fmaxf(pos, 1e-30f));
        }
#pragma unroll
        for (int m = 1; m < 64; m <<= 1) v += __shfl_xor(v, m, 64);
        if (lane == 0) ws2[w] = v;
        __syncthreads();
        if (tid == 0) {
            float s = 0.f;
#pragma unroll
            for (int j = 0; j < 8; ++j) s += ws2[j];
            out[0] = s * (1.f / 1024.f);
        }
    }
}

extern "C" void kernel_launch(void* const* d_in, const int* in_sizes, int n_in,
                              void* d_out, int out_size, void* d_ws, size_t ws_size,
                              hipStream_t stream) {
    const float* emb = (const float*)d_in[0];
    // d_in[1] = labels (unused; structure fixed by construction)
    const float* alpha_p = (const float*)d_in[2];
    const float* beta_p = (const float*)d_in[3];

    unsigned short* cent = (unsigned short*)d_ws;          // 1024*512 bf16 = 1 MB
    unsigned short* test = cent + (size_t)N_SPK * D;       // 16384*512 bf16 = 16 MB
    float* g_row = (float*)(test + (size_t)N_TEST_ROWS * D);
    float* g_pos = g_row + N_SPK;
    unsigned int* cnt = (unsigned int*)(g_pos + N_SPK);

    prep_kernel<<<N_SPK + N_TEST_ROWS / 4, 256, 0, stream>>>(emb, cent, test,
                                                             g_row, g_pos, cnt);

    gemm_kernel<<<NBLK_GEMM, 512, 0, stream>>>(cent, test, alpha_p, beta_p,
                                               g_row, g_pos, cnt, (float*)d_out);
}

// Round 10
// 53.180 us; speedup vs baseline: 1.8560x; 1.3418x over previous
//
#include <hip/hip_runtime.h>
#include <math.h>

#define N_SPK 1024
#define M_UTT 32
#define M_ENR 16
#define M_TEST 16
#define D 512
#define N_TEST_ROWS (N_SPK * M_TEST)   // 16384

// gemm: block = 1024 thr (16 waves), tile 128spk x 512test, wave = 128 x 32.
// grid = 8 x 32 = 256 blocks = 1 per CU, 16 waves/CU = 4 waves/SIMD (the
// 1024-thread block forces regs <= 128/thread: acc 64 AGPR + ~55 VGPR fits).
// A (cent) panel LDS-resident (XOR-swizzled), B (test) streamed L2->reg
// (2-deep ring), barrier-free K-loop — exact R3 loop body, re-partitioned.

typedef __attribute__((ext_vector_type(4))) float f32x4;
typedef __attribute__((ext_vector_type(8))) short short8;
typedef __attribute__((ext_vector_type(8))) unsigned short ushort8;

typedef const __attribute__((address_space(1))) void g_void;
typedef __attribute__((address_space(3))) void lds_void;

__device__ __forceinline__ unsigned short f2bf(float f) {
    unsigned int u = __float_as_uint(f);
    u += 0x7FFF + ((u >> 16) & 1);   // round-to-nearest-even
    return (unsigned short)(u >> 16);
}

// ---------------------------------------------------------------------------
// Kernel 1: centroids + test-row normalize; blocks [0,4) also zero g_row/g_pos.
// (verbatim from the 49.1 µs round-3 kernel)
// ---------------------------------------------------------------------------
__global__ __launch_bounds__(256) void prep_kernel(const float* __restrict__ emb,
                                                   unsigned short* __restrict__ cent,
                                                   unsigned short* __restrict__ test,
                                                   float* __restrict__ g_row,
                                                   float* __restrict__ g_pos) {
    const int b = blockIdx.x;
    const int tid = threadIdx.x;
    const int lane = tid & 63;
    const int wid = tid >> 6;

    if (b < 4) {
        g_row[b * 256 + tid] = 0.f;
        g_pos[b * 256 + tid] = 0.f;
    }

    if (b < N_SPK) {
        const float* base = emb + (size_t)b * M_UTT * D;
        float a0 = 0.f, a1 = 0.f;
#pragma unroll
        for (int u = 0; u < M_ENR; ++u) {
            a0 += base[u * D + tid];
            a1 += base[u * D + tid + 256];
        }
        a0 *= (1.f / 16.f);
        a1 *= (1.f / 16.f);
        float ss = a0 * a0 + a1 * a1;
#pragma unroll
        for (int m = 1; m < 64; m <<= 1) ss += __shfl_xor(ss, m, 64);
        __shared__ float wss[4];
        if (lane == 0) wss[wid] = ss;
        __syncthreads();
        const float tot = wss[0] + wss[1] + wss[2] + wss[3];
        const float inv = 1.f / fmaxf(sqrtf(tot), 1e-8f);
        cent[b * D + tid] = f2bf(a0 * inv);
        cent[b * D + tid + 256] = f2bf(a1 * inv);
    } else {
        const int r = (b - N_SPK) * 4 + wid;   // test row 0..16383
        const int s = r >> 4, t = r & 15;
        const float* row = emb + ((size_t)s * M_UTT + M_ENR + t) * D;
        const f32x4* rv = (const f32x4*)row;
        const f32x4 v0 = rv[lane * 2];
        const f32x4 v1 = rv[lane * 2 + 1];
        float ss = v0[0]*v0[0] + v0[1]*v0[1] + v0[2]*v0[2] + v0[3]*v0[3]
                 + v1[0]*v1[0] + v1[1]*v1[1] + v1[2]*v1[2] + v1[3]*v1[3];
#pragma unroll
        for (int m = 1; m < 64; m <<= 1) ss += __shfl_xor(ss, m, 64);
        const float inv = 1.f / fmaxf(sqrtf(ss), 1e-8f);
        ushort8 o;
        o[0] = f2bf(v0[0] * inv); o[1] = f2bf(v0[1] * inv);
        o[2] = f2bf(v0[2] * inv); o[3] = f2bf(v0[3] * inv);
        o[4] = f2bf(v1[0] * inv); o[5] = f2bf(v1[1] * inv);
        o[6] = f2bf(v1[2] * inv); o[7] = f2bf(v1[3] * inv);
        *(ushort8*)&test[(size_t)r * D + lane * 8] = o;
    }
}

// ---------------------------------------------------------------------------
// Kernel 2: R3 loop body, 16-wave partition (4 waves/SIMD).
// ---------------------------------------------------------------------------
__global__ __launch_bounds__(1024) void gemm_kernel(const unsigned short* __restrict__ A,  // cent 1024x512
                                                    const unsigned short* __restrict__ B,  // test 16384x512
                                                    const float* __restrict__ alpha_p,
                                                    const float* __restrict__ beta_p,
                                                    float* __restrict__ g_row,
                                                    float* __restrict__ g_pos) {
    __shared__ __align__(16) unsigned short As[128 * 512];   // 128 KB, swizzled
    __shared__ float rowsum[128];
    __shared__ float possum[128];

    const int tid = threadIdx.x;
    const int lane = tid & 63;
    const int w = tid >> 6;          // wave 0..15, owns test cols [w*32, +32)
    const int l15 = lane & 15;

    const int raw = blockIdx.x;
    const int wg = (raw & 7) * 32 + (raw >> 3);   // XCD swizzle (8 x 32)
    const int bi = wg & 7;           // speaker panel (128 rows)
    const int bj = wg >> 3;          // test panel (512 cols)
    const int row0 = bi * 128, col0 = bj * 512;
    const bool has_diag = ((bj >> 2) == bi);

    // ---- stage cent panel once: LDS[r][e] = A[row0+r][ e ^ ((r&7)<<3) ]
    // 16 waves x 8 rounds; r&7 == w&7 (wave-uniform swizzle constant).
#pragma unroll
    for (int it = 0; it < 8; ++it) {
        const int r = it * 16 + w;
        const int src = (row0 + r) * D + ((lane * 8) ^ ((r & 7) << 3));
        __builtin_amdgcn_global_load_lds((g_void*)&A[src],
                                         (lds_void*)&As[r * D], 16, 0, 0);
    }
    if (tid < 128) { rowsum[tid] = 0.f; possum[tid] = 0.f; }

    const float alpha = *alpha_p;
    const float beta = *beta_p;

    const int bcol = col0 + w * 32;
    const unsigned short* bp[2];
#pragma unroll
    for (int ni = 0; ni < 2; ++ni)
        bp[ni] = &B[(size_t)(bcol + ni * 16 + l15) * D + (lane >> 4) * 8];

    // swizzled LDS read offset: (kk + (lane>>4)*8) ^ ((lane&7)<<3) = kk ^ hs
    const int hs = ((lane >> 4) * 8) ^ ((lane & 7) << 3);
    const int arow_base = l15 * D;

    f32x4 acc[8][2] = {};
    short8 b0[2], b1[2];

#define LOADB(dst, kk)                                              \
    {                                                               \
        _Pragma("unroll") for (int ni = 0; ni < 2; ++ni)            \
            dst[ni] = *(const short8*)(bp[ni] + (kk));              \
    }

#define STEP(bfr, kk)                                                          \
    {                                                                          \
        const int ofs_ = (kk) ^ hs;                                            \
        _Pragma("unroll") for (int mi = 0; mi < 8; ++mi) {                     \
            const short8 af_ = *(const short8*)&As[mi * 16 * D + arow_base + ofs_]; \
            _Pragma("unroll") for (int ni = 0; ni < 2; ++ni)                   \
                acc[mi][ni] = __builtin_amdgcn_mfma_f32_16x16x32_bf16(         \
                    af_, bfr[ni], acc[mi][ni], 0, 0, 0);                       \
        }                                                                      \
    }

    LOADB(b0, 0); LOADB(b1, 32);
    __syncthreads();   // A staged

    for (int ko = 0; ko < D; ko += 64) {
        STEP(b0, ko);       LOADB(b0, (ko + 64) & (D - 1));   // wrap: harmless reload
        STEP(b1, ko + 32);  LOADB(b1, (ko + 96) & (D - 1));
    }
#undef LOADB
#undef STEP

    // ---- epilogue: e = exp(alpha*s + beta); row totals + diagonal sums.
    // C/D layout (16x16x32): col = lane&15, row = (lane>>4)*4 + reg   [m89]
#pragma unroll
    for (int mi = 0; mi < 8; ++mi) {
#pragma unroll
        for (int r = 0; r < 4; ++r) {
            const int lrow = mi * 16 + ((lane >> 4) << 2) + r;
            const int grow = row0 + lrow;
            float tot = 0.f, pos = 0.f;
#pragma unroll
            for (int ni = 0; ni < 2; ++ni) {
                const int gcol = bcol + ni * 16 + l15;
                const float e = __expf(fmaf(alpha, acc[mi][ni][r], beta));
                tot += e;
                if (has_diag) pos += ((gcol >> 4) == grow) ? e : 0.f;
            }
#pragma unroll
            for (int m = 1; m < 16; m <<= 1) tot += __shfl_xor(tot, m, 64);
            if (has_diag) {
#pragma unroll
                for (int m = 1; m < 16; m <<= 1) pos += __shfl_xor(pos, m, 64);
            }
            if (l15 == 0) {
                atomicAdd(&rowsum[lrow], tot);
                if (has_diag) atomicAdd(&possum[lrow], pos);
            }
        }
    }
    __syncthreads();
    if (tid < 128) {
        atomicAdd(&g_row[row0 + tid], rowsum[tid]);
        if (has_diag) atomicAdd(&g_pos[row0 + tid], possum[tid]);
    }
}

// ---------------------------------------------------------------------------
// Kernel 3: loss = mean(log(tot - pos) - log(pos)) — shfl-based, 1 barrier.
// ---------------------------------------------------------------------------
__global__ __launch_bounds__(1024) void finalize_kernel(const float* __restrict__ g_row,
                                                        const float* __restrict__ g_pos,
                                                        float* __restrict__ out) {
    __shared__ float wsum[16];
    const int i = threadIdx.x;
    const int lane = i & 63, wid = i >> 6;
    const float pos = g_pos[i];
    const float neg = g_row[i] - pos;
    float v = logf(fmaxf(neg, 1e-30f)) - logf(fmaxf(pos, 1e-30f));
#pragma unroll
    for (int m = 1; m < 64; m <<= 1) v += __shfl_xor(v, m, 64);
    if (lane == 0) wsum[wid] = v;
    __syncthreads();
    if (i < 64) {
        float s = (i < 16) ? wsum[i] : 0.f;
#pragma unroll
        for (int m = 1; m < 16; m <<= 1) s += __shfl_xor(s, m, 64);
        if (i == 0) out[0] = s * (1.f / 1024.f);
    }
}

extern "C" void kernel_launch(void* const* d_in, const int* in_sizes, int n_in,
                              void* d_out, int out_size, void* d_ws, size_t ws_size,
                              hipStream_t stream) {
    const float* emb = (const float*)d_in[0];
    // d_in[1] = labels (unused; structure fixed by construction)
    const float* alpha_p = (const float*)d_in[2];
    const float* beta_p = (const float*)d_in[3];

    unsigned short* cent = (unsigned short*)d_ws;          // 1024*512 bf16 = 1 MB
    unsigned short* test = cent + (size_t)N_SPK * D;       // 16384*512 bf16 = 16 MB
    float* g_row = (float*)(test + (size_t)N_TEST_ROWS * D);
    float* g_pos = g_row + N_SPK;

    prep_kernel<<<N_SPK + N_TEST_ROWS / 4, 256, 0, stream>>>(emb, cent, test, g_row, g_pos);

    gemm_kernel<<<256, 1024, 0, stream>>>(cent, test, alpha_p, beta_p, g_row, g_pos);

    finalize_kernel<<<1, 1024, 0, stream>>>(g_row, g_pos, (float*)d_out);
}